// Round 9
// baseline (204.935 us; speedup 1.0000x reference)
//
#include <hip/hip_runtime.h>
#include <math.h>

typedef __bf16 bf16x8 __attribute__((ext_vector_type(8)));
typedef float f32x4 __attribute__((ext_vector_type(4)));

__device__ __forceinline__ unsigned f2bf(float f) {
    union { float f; unsigned u; } v; v.f = f;
    return (v.u + 0x7FFFu + ((v.u >> 16) & 1u)) >> 16;
}

// async global->LDS, 16B per lane. LDS dest = wave-uniform base + lane*16.
__device__ __forceinline__ void gload16(const ushort* g, ushort* l) {
    __builtin_amdgcn_global_load_lds(
        (const __attribute__((address_space(1))) void*)g,
        (__attribute__((address_space(3))) void*)l, 16, 0, 0);
}

// ---------------------------------------------------------------------------
// Fused input canonicalization (ONE launch): fp32 -> bf16 for all 3 inputs.
// Segment sizes are compile-time known: x 4M, w_attn 3M, w_proj 1M elems.
// 4096 blocks x 256 thr x 8 elems = 8.39M elems.
// ---------------------------------------------------------------------------
__device__ __forceinline__ bool src_is_fp32(const unsigned* s) {
    int sane = 0;
#pragma unroll
    for (int i = 0; i < 64; ++i) {
        unsigned lo = s[i] & 0xFFFFu;
        unsigned e = (lo >> 7) & 0xFF;
        if (lo == 0u || (e >= 100u && e <= 140u)) sane++;
    }
    return sane < 48;
}

__global__ __launch_bounds__(256) void tobf16_all_kernel(
    const unsigned* __restrict__ s0, const unsigned* __restrict__ s1,
    const unsigned* __restrict__ s2,
    ushort* __restrict__ d0, ushort* __restrict__ d1, ushort* __restrict__ d2) {
    const int bx = blockIdx.x;
    const unsigned* src;
    ushort* dst;
    int lb;
    if (bx < 2048)      { src = s0; dst = d0; lb = bx; }
    else if (bx < 3584) { src = s1; dst = d1; lb = bx - 2048; }
    else                { src = s2; dst = d2; lb = bx - 3584; }
    const int i = lb * 2048 + threadIdx.x * 8;
    if (src_is_fp32(src)) {
        const float* fs = (const float*)src;
        float4 f0 = *(const float4*)(fs + i);
        float4 f1 = *(const float4*)(fs + i + 4);
        uint4 o;
        o.x = f2bf(f0.x) | (f2bf(f0.y) << 16);
        o.y = f2bf(f0.z) | (f2bf(f0.w) << 16);
        o.z = f2bf(f1.x) | (f2bf(f1.y) << 16);
        o.w = f2bf(f1.z) | (f2bf(f1.w) << 16);
        *(uint4*)(dst + i) = o;
    } else {
        *(uint4*)(dst + i) = *(const uint4*)((const ushort*)src + i);
    }
}

// ---------------------------------------------------------------------------
// GEMM1 + RoPE + head-major remap. (unchanged from round 8)
// ---------------------------------------------------------------------------
constexpr int GBM = 128, GBN = 128, GBK = 32;

__global__ __launch_bounds__(256) void gemm_qkv_rope_kernel(
    const ushort* __restrict__ A, const ushort* __restrict__ Bmat,
    ushort* __restrict__ qkvh, int K) {
    __shared__ ushort As[GBM * GBK];
    __shared__ ushort Bs[GBN * GBK];

    const int tid  = threadIdx.x;
    const int lane = tid & 63;
    const int wv   = tid >> 6;
    const int wm   = (wv >> 1) * 64;
    const int wn   = (wv & 1) * 64;

    const ushort* Ab = A + (size_t)blockIdx.x * GBM * K;
    const ushort* Bb = Bmat + (size_t)blockIdx.y * GBN * K;

    f32x4 acc[4][4];
#pragma unroll
    for (int i = 0; i < 4; i++)
#pragma unroll
        for (int j = 0; j < 4; j++) acc[i][j] = (f32x4){0.f, 0.f, 0.f, 0.f};

    const int srow = tid >> 2;
    const int scol = (tid & 3) * 8;
    const int fr = lane & 15;
    const int fk = (lane >> 4) * 8;
    ushort* adst = As + wv * 512;
    ushort* bdst = Bs + wv * 512;

    for (int k0 = 0; k0 < K; k0 += GBK) {
        __syncthreads();
        gload16(Ab + (size_t)srow * K + k0 + scol,        adst);
        gload16(Ab + (size_t)(srow + 64) * K + k0 + scol, adst + 2048);
        gload16(Bb + (size_t)srow * K + k0 + scol,        bdst);
        gload16(Bb + (size_t)(srow + 64) * K + k0 + scol, bdst + 2048);
        __syncthreads();

        bf16x8 af[4], bfr[4];
#pragma unroll
        for (int i = 0; i < 4; i++)
            af[i] = *(const bf16x8*)(As + (wm + i * 16 + fr) * GBK + fk);
#pragma unroll
        for (int j = 0; j < 4; j++)
            bfr[j] = *(const bf16x8*)(Bs + (wn + j * 16 + fr) * GBK + fk);
#pragma unroll
        for (int i = 0; i < 4; i++)
#pragma unroll
            for (int j = 0; j < 4; j++)
                acc[i][j] = __builtin_amdgcn_mfma_f32_16x16x32_bf16(af[i], bfr[j], acc[i][j], 0, 0, 0);
    }

    const int crow0 = (lane >> 4) * 4;
    const int col0  = blockIdx.y * GBN + wn;       // 64-aligned
    const int which = col0 >> 10;                  // 0=q 1=k 2=v
    const int hh    = (col0 >> 6) & 15;
    ushort* outp = qkvh + (size_t)which * 4194304 + (size_t)hh * 131072;

    if (which < 2) {
        const float inva = exp2f((float)fr * -0.41524101186f);
        const float invb = exp2f((float)(fr + 16) * -0.41524101186f);
        const float qs = (which == 0) ? 0.125f : 1.0f;
#pragma unroll
        for (int i = 0; i < 4; i++)
#pragma unroll
            for (int r = 0; r < 4; r++) {
                int row = blockIdx.x * GBM + wm + i * 16 + crow0 + r;
                int t = row & 2047;
                size_t ob = ((size_t)(row >> 11)) * 2097152 + (size_t)t * 64;
                float sa, ca, sb, cb;
                __sincosf((float)t * inva, &sa, &ca);
                __sincosf((float)t * invb, &sb, &cb);
                float q0 = acc[i][0][r], q1 = acc[i][1][r];
                float q2 = acc[i][2][r], q3 = acc[i][3][r];
                float n0 = (q0 * ca + q2 * sa) * qs;
                float n1 = (q1 * cb + q3 * sb) * qs;
                float n2 = (q2 * ca - q0 * sa) * qs;
                float n3 = (q3 * cb - q1 * sb) * qs;
                outp[ob + fr]      = (ushort)f2bf(n0);
                outp[ob + 16 + fr] = (ushort)f2bf(n1);
                outp[ob + 32 + fr] = (ushort)f2bf(n2);
                outp[ob + 48 + fr] = (ushort)f2bf(n3);
            }
    } else {
#pragma unroll
        for (int i = 0; i < 4; i++)
#pragma unroll
            for (int r = 0; r < 4; r++) {
                int row = blockIdx.x * GBM + wm + i * 16 + crow0 + r;
                int t = row & 2047;
                size_t ob = ((size_t)(row >> 11)) * 2097152 + (size_t)t * 64;
#pragma unroll
                for (int j = 0; j < 4; j++)
                    outp[ob + j * 16 + fr] = (ushort)f2bf(acc[i][j][r]);
            }
    }
}

// ---------------------------------------------------------------------------
// Plain GEMM for the output projection (fp32 out). m97 pattern. (unchanged)
// ---------------------------------------------------------------------------
__global__ __launch_bounds__(256) void gemm_bt_kernel(
    const ushort* __restrict__ A, const ushort* __restrict__ Bmat,
    float* __restrict__ C, int M, int N, int K) {
    __shared__ ushort As[GBM * GBK];
    __shared__ ushort Bs[GBN * GBK];

    const int tid  = threadIdx.x;
    const int lane = tid & 63;
    const int wv   = tid >> 6;
    const int wm   = (wv >> 1) * 64;
    const int wn   = (wv & 1) * 64;

    const ushort* Ab = A + (size_t)blockIdx.x * GBM * K;
    const ushort* Bb = Bmat + (size_t)blockIdx.y * GBN * K;

    f32x4 acc[4][4];
#pragma unroll
    for (int i = 0; i < 4; i++)
#pragma unroll
        for (int j = 0; j < 4; j++) acc[i][j] = (f32x4){0.f, 0.f, 0.f, 0.f};

    const int srow = tid >> 2;
    const int scol = (tid & 3) * 8;
    const int fr = lane & 15;
    const int fk = (lane >> 4) * 8;
    ushort* adst = As + wv * 512;
    ushort* bdst = Bs + wv * 512;

    for (int k0 = 0; k0 < K; k0 += GBK) {
        __syncthreads();
        gload16(Ab + (size_t)srow * K + k0 + scol,        adst);
        gload16(Ab + (size_t)(srow + 64) * K + k0 + scol, adst + 2048);
        gload16(Bb + (size_t)srow * K + k0 + scol,        bdst);
        gload16(Bb + (size_t)(srow + 64) * K + k0 + scol, bdst + 2048);
        __syncthreads();

        bf16x8 af[4], bfr[4];
#pragma unroll
        for (int i = 0; i < 4; i++)
            af[i] = *(const bf16x8*)(As + (wm + i * 16 + fr) * GBK + fk);
#pragma unroll
        for (int j = 0; j < 4; j++)
            bfr[j] = *(const bf16x8*)(Bs + (wn + j * 16 + fr) * GBK + fk);
#pragma unroll
        for (int i = 0; i < 4; i++)
#pragma unroll
            for (int j = 0; j < 4; j++)
                acc[i][j] = __builtin_amdgcn_mfma_f32_16x16x32_bf16(af[i], bfr[j], acc[i][j], 0, 0, 0);
    }

    const int crow0 = (lane >> 4) * 4;
#pragma unroll
    for (int i = 0; i < 4; i++)
#pragma unroll
        for (int j = 0; j < 4; j++)
#pragma unroll
            for (int r = 0; r < 4; r++) {
                int row = blockIdx.x * GBM + wm + i * 16 + crow0 + r;
                int col = blockIdx.y * GBN + wn + j * 16 + fr;
                C[(size_t)row * N + col] = acc[i][j][r];
            }
}

// ---------------------------------------------------------------------------
// Causal flash attention v4. Bq=64 (256 thr = 4 waves), Bk=128, dense
// head-major K/V. Grid 16x32 = 512 blocks (2/CU co-resident; LDS 53 KB -> 3
// max). Block p does q-blocks p and 31-p: uniform 17 chunk-iters per block.
// Fixed-max softmax (q pre-scaled 0.125 in GEMM1 epilogue).
// 2 barriers/iter: Ps has its own region; the P round-trip is same-wave
// (each wave reads only its own tile) -> DS pipe in-order per wave; an
// asm memory clobber stops compiler reordering (rounds 1/2 showed identical
// behavior with/without the barrier). Prefetch issued AFTER barrier B so the
// barrier's vmcnt drain can't collapse the overlap window.
// ---------------------------------------------------------------------------
#define NEG_BIG (-1e30f)
constexpr int LPK = 72;    // Ks row: 64 d + 8 pad
constexpr int LPV = 136;   // Vt/Ps row: 128 keys + 8 pad

__global__ __launch_bounds__(256) void attn_kernel(const ushort* __restrict__ qkvh,
                                                   ushort* __restrict__ y) {
    __shared__ ushort Ks[128 * LPK];    // 18432 B
    __shared__ ushort Vt[64 * LPV];     // 17408 B
    __shared__ ushort Ps[4][16 * LPV];  // 17408 B

    const int tid  = threadIdx.x;
    const int lane = tid & 63;
    const int wv   = tid >> 6;
    const int pid  = blockIdx.x;        // 0..15
    const int bh   = blockIdx.y;        // 0..31
    const int b    = bh >> 4, h = bh & 15;

    const ushort* qp = qkvh + (size_t)b * 2097152 + (size_t)h * 131072;
    const ushort* kp = qp + 4194304;
    const ushort* vp = qp + 8388608;

    const int fr = lane & 15;
    const int fq = lane >> 4;
    const int fk = fq * 8;

    const int srow = tid >> 1;          // K staging: key 0..127
    const int scol = (tid & 1) * 32;    // half-row of 32 d
    const int vkey = tid & 127;         // V staging: key
    const int vd0  = (tid >> 7) * 32;   // d-group of 32

#pragma unroll 1
    for (int seg = 0; seg < 2; ++seg) {
        const int qb = seg ? (31 - pid) : pid;    // 64-row q-block, 0..31
        const int nIt = (qb + 2) >> 1;            // chunks of 128 keys

        const int qrow = qb * 64 + wv * 16 + fr;
        bf16x8 qf0 = *(const bf16x8*)(qp + (size_t)qrow * 64 + fk);
        bf16x8 qf1 = *(const bf16x8*)(qp + (size_t)qrow * 64 + 32 + fk);

        f32x4 o[4];
        o[0] = o[1] = o[2] = o[3] = (f32x4){0.f, 0.f, 0.f, 0.f};
        float lacc[4] = {0.f, 0.f, 0.f, 0.f};

        uint4 kr0, kr1, kr2, kr3, vr0, vr1, vr2, vr3;
        {   // prefetch chunk 0 (dense: K chunk is 16 KB contiguous)
            const ushort* sk = kp + (size_t)srow * 64 + scol;
            kr0 = *(const uint4*)(sk);
            kr1 = *(const uint4*)(sk + 8);
            kr2 = *(const uint4*)(sk + 16);
            kr3 = *(const uint4*)(sk + 24);
            const ushort* sv = vp + (size_t)vkey * 64 + vd0;
            vr0 = *(const uint4*)(sv);
            vr1 = *(const uint4*)(sv + 8);
            vr2 = *(const uint4*)(sv + 16);
            vr3 = *(const uint4*)(sv + 24);
        }

#pragma unroll 1
        for (int it = 0; it < nIt; ++it) {
            const int k0 = it * 128;
            __syncthreads();   // A: prior PV reads of Vt done
            *(uint4*)(Ks + srow * LPK + scol)      = kr0;
            *(uint4*)(Ks + srow * LPK + scol + 8)  = kr1;
            *(uint4*)(Ks + srow * LPK + scol + 16) = kr2;
            *(uint4*)(Ks + srow * LPK + scol + 24) = kr3;
            {   // V transpose from regs
                unsigned w[16] = {vr0.x, vr0.y, vr0.z, vr0.w, vr1.x, vr1.y, vr1.z, vr1.w,
                                  vr2.x, vr2.y, vr2.z, vr2.w, vr3.x, vr3.y, vr3.z, vr3.w};
#pragma unroll
                for (int jj = 0; jj < 16; ++jj) {
                    Vt[(vd0 + 2 * jj)     * LPV + vkey] = (ushort)(w[jj] & 0xFFFFu);
                    Vt[(vd0 + 2 * jj + 1) * LPV + vkey] = (ushort)(w[jj] >> 16);
                }
            }
            __syncthreads();   // B: staging visible
            if (it + 1 < nIt) {   // prefetch next chunk AFTER the barrier
                const ushort* sk = kp + (size_t)(k0 + 128 + srow) * 64 + scol;
                kr0 = *(const uint4*)(sk);
                kr1 = *(const uint4*)(sk + 8);
                kr2 = *(const uint4*)(sk + 16);
                kr3 = *(const uint4*)(sk + 24);
                const ushort* sv = vp + (size_t)(k0 + 128 + vkey) * 64 + vd0;
                vr0 = *(const uint4*)(sv);
                vr1 = *(const uint4*)(sv + 8);
                vr2 = *(const uint4*)(sv + 16);
                vr3 = *(const uint4*)(sv + 24);
            }

            f32x4 s[8];
#pragma unroll
            for (int j = 0; j < 8; ++j) {
                bf16x8 kf0 = *(const bf16x8*)(Ks + (j * 16 + fr) * LPK + fk);
                bf16x8 kf1 = *(const bf16x8*)(Ks + (j * 16 + fr) * LPK + 32 + fk);
                f32x4 z = (f32x4){0.f, 0.f, 0.f, 0.f};
                z = __builtin_amdgcn_mfma_f32_16x16x32_bf16(qf0, kf0, z, 0, 0, 0);
                z = __builtin_amdgcn_mfma_f32_16x16x32_bf16(qf1, kf1, z, 0, 0, 0);
                s[j] = z;
            }
            if (it + 1 < nIt) {   // interior chunk: no mask
#pragma unroll
                for (int j = 0; j < 8; ++j)
#pragma unroll
                    for (int r = 0; r < 4; ++r) {
                        float p = __expf(s[j][r]);
                        s[j][r] = p;
                        lacc[r] += p;
                    }
            } else {              // diagonal-straddling chunk
                const int rowg = qb * 64 + wv * 16 + fq * 4;
#pragma unroll
                for (int j = 0; j < 8; ++j)
#pragma unroll
                    for (int r = 0; r < 4; ++r) {
                        float v = s[j][r];
                        if ((k0 + j * 16 + fr) > (rowg + r)) v = NEG_BIG;
                        float p = __expf(v);
                        s[j][r] = p;
                        lacc[r] += p;
                    }
            }

            // P round-trip: same-wave LDS region, DS pipe in-order per wave.
            ushort* pw = Ps[wv];
#pragma unroll
            for (int j = 0; j < 8; ++j)
#pragma unroll
                for (int r = 0; r < 4; ++r)
                    pw[(fq * 4 + r) * LPV + j * 16 + fr] = (ushort)f2bf(s[j][r]);
            __asm__ volatile("" ::: "memory");   // stop compiler reordering

#pragma unroll
            for (int kk = 0; kk < 4; ++kk) {
                bf16x8 pf = *(const bf16x8*)(pw + fr * LPV + kk * 32 + fk);
#pragma unroll
                for (int j = 0; j < 4; ++j) {
                    bf16x8 vf = *(const bf16x8*)(Vt + (j * 16 + fr) * LPV + kk * 32 + fk);
                    o[j] = __builtin_amdgcn_mfma_f32_16x16x32_bf16(pf, vf, o[j], 0, 0, 0);
                }
            }
        }

        // epilogue: reduce lacc over the 16 key-lanes, store y[b][t][h*64+d]
#pragma unroll
        for (int msk = 1; msk < 16; msk <<= 1)
#pragma unroll
            for (int r = 0; r < 4; ++r)
                lacc[r] += __shfl_xor(lacc[r], msk, 64);
#pragma unroll
        for (int j = 0; j < 4; ++j)
#pragma unroll
            for (int r = 0; r < 4; ++r) {
                int row = qb * 64 + wv * 16 + fq * 4 + r;
                y[((size_t)b * 2048 + row) * 1024 + h * 64 + j * 16 + fr] =
                    (ushort)f2bf(o[j][r] / lacc[r]);
            }
    }
}

// ---------------------------------------------------------------------------
extern "C" void kernel_launch(void* const* d_in, const int* in_sizes, int n_in,
                              void* d_out, int out_size, void* d_ws, size_t ws_size,
                              hipStream_t stream) {
    const int nx = in_sizes[0];   // 4194304
    const int na = in_sizes[1];   // 3145728
    const int np = in_sizes[2];   // 1048576

    ushort* qkvh = (ushort*)d_ws;                      // [3][2][16][2048][64]
    ushort* yb   = qkvh + (size_t)3 * 4194304;
    ushort* xb   = yb + (size_t)4096 * 1024;
    ushort* wab  = xb + nx;
    ushort* wpb  = wab + na;
    size_t need = ((size_t)3 * 4194304 + (size_t)4096 * 1024 + nx + na + np) * 2;
    if (ws_size < need) return;

    tobf16_all_kernel<<<dim3(4096), 256, 0, stream>>>(
        (const unsigned*)d_in[0], (const unsigned*)d_in[1], (const unsigned*)d_in[2],
        xb, wab, wpb);

    gemm_qkv_rope_kernel<<<dim3(32, 24), 256, 0, stream>>>(xb, wab, qkvh, 1024);
    attn_kernel<<<dim3(16, 32), 256, 0, stream>>>(qkvh, yb);
    gemm_bt_kernel<<<dim3(32, 8), 256, 0, stream>>>(yb, wpb, (float*)d_out, 4096, 1024, 1024);
}

// Round 10
// 201.483 us; speedup vs baseline: 1.0171x; 1.0171x over previous
//
#include <hip/hip_runtime.h>
#include <math.h>

typedef __bf16 bf16x8 __attribute__((ext_vector_type(8)));
typedef float f32x4 __attribute__((ext_vector_type(4)));

__device__ __forceinline__ unsigned f2bf(float f) {
    union { float f; unsigned u; } v; v.f = f;
    return (v.u + 0x7FFFu + ((v.u >> 16) & 1u)) >> 16;
}

// async global->LDS, 16B per lane. LDS dest = wave-uniform base + lane*16.
__device__ __forceinline__ void gload16(const ushort* g, ushort* l) {
    __builtin_amdgcn_global_load_lds(
        (const __attribute__((address_space(1))) void*)g,
        (__attribute__((address_space(3))) void*)l, 16, 0, 0);
}

// ---------------------------------------------------------------------------
// Fused input canonicalization (one launch): fp32 -> bf16 for all 3 inputs.
// ---------------------------------------------------------------------------
__device__ __forceinline__ bool src_is_fp32(const unsigned* s) {
    int sane = 0;
#pragma unroll
    for (int i = 0; i < 64; ++i) {
        unsigned lo = s[i] & 0xFFFFu;
        unsigned e = (lo >> 7) & 0xFF;
        if (lo == 0u || (e >= 100u && e <= 140u)) sane++;
    }
    return sane < 48;
}

__global__ __launch_bounds__(256) void tobf16_all_kernel(
    const unsigned* __restrict__ s0, const unsigned* __restrict__ s1,
    const unsigned* __restrict__ s2,
    ushort* __restrict__ d0, ushort* __restrict__ d1, ushort* __restrict__ d2) {
    const int bx = blockIdx.x;
    const unsigned* src;
    ushort* dst;
    int lb;
    if (bx < 2048)      { src = s0; dst = d0; lb = bx; }
    else if (bx < 3584) { src = s1; dst = d1; lb = bx - 2048; }
    else                { src = s2; dst = d2; lb = bx - 3584; }
    const int i = lb * 2048 + threadIdx.x * 8;
    if (src_is_fp32(src)) {
        const float* fs = (const float*)src;
        float4 f0 = *(const float4*)(fs + i);
        float4 f1 = *(const float4*)(fs + i + 4);
        uint4 o;
        o.x = f2bf(f0.x) | (f2bf(f0.y) << 16);
        o.y = f2bf(f0.z) | (f2bf(f0.w) << 16);
        o.z = f2bf(f1.x) | (f2bf(f1.y) << 16);
        o.w = f2bf(f1.z) | (f2bf(f1.w) << 16);
        *(uint4*)(dst + i) = o;
    } else {
        *(uint4*)(dst + i) = *(const uint4*)((const ushort*)src + i);
    }
}

// ---------------------------------------------------------------------------
// GEMM K-loop v2: double-buffered LDS + global_load_lds issued one full
// compute-phase before its consuming barrier (1 barrier/iter). Removes the
// m97 zero-overlap vmcnt(0) drain stall (worst at short K).
// ---------------------------------------------------------------------------
constexpr int GBM = 128, GBN = 128, GBK = 32;

// ---- GEMM1 + RoPE + head-major remap --------------------------------------
__global__ __launch_bounds__(256) void gemm_qkv_rope_kernel(
    const ushort* __restrict__ A, const ushort* __restrict__ Bmat,
    ushort* __restrict__ qkvh, int K) {
    __shared__ ushort As[2][GBM * GBK];   // 2 x 8 KB
    __shared__ ushort Bs[2][GBN * GBK];   // 2 x 8 KB

    const int tid  = threadIdx.x;
    const int lane = tid & 63;
    const int wv   = tid >> 6;
    const int wm   = (wv >> 1) * 64;
    const int wn   = (wv & 1) * 64;

    const ushort* Ab = A + (size_t)blockIdx.x * GBM * K;
    const ushort* Bb = Bmat + (size_t)blockIdx.y * GBN * K;

    f32x4 acc[4][4];
#pragma unroll
    for (int i = 0; i < 4; i++)
#pragma unroll
        for (int j = 0; j < 4; j++) acc[i][j] = (f32x4){0.f, 0.f, 0.f, 0.f};

    const int srow = tid >> 2;
    const int scol = (tid & 3) * 8;
    const int fr = lane & 15;
    const int fk = (lane >> 4) * 8;
    const int nK = K >> 5;

    // prologue: chunk 0 -> buf 0
    gload16(Ab + (size_t)srow * K + scol,        As[0] + wv * 512);
    gload16(Ab + (size_t)(srow + 64) * K + scol, As[0] + wv * 512 + 2048);
    gload16(Bb + (size_t)srow * K + scol,        Bs[0] + wv * 512);
    gload16(Bb + (size_t)(srow + 64) * K + scol, Bs[0] + wv * 512 + 2048);

#pragma unroll 1
    for (int it = 0; it < nK; ++it) {
        const int cur = it & 1;
        __syncthreads();   // drains chunk-it DMA (issued a full phase ago)
        if (it + 1 < nK) { // issue chunk it+1 into the other buffer
            const int k0 = (it + 1) << 5, nxt = cur ^ 1;
            gload16(Ab + (size_t)srow * K + k0 + scol,        As[nxt] + wv * 512);
            gload16(Ab + (size_t)(srow + 64) * K + k0 + scol, As[nxt] + wv * 512 + 2048);
            gload16(Bb + (size_t)srow * K + k0 + scol,        Bs[nxt] + wv * 512);
            gload16(Bb + (size_t)(srow + 64) * K + k0 + scol, Bs[nxt] + wv * 512 + 2048);
        }
        bf16x8 af[4], bfr[4];
#pragma unroll
        for (int i = 0; i < 4; i++)
            af[i] = *(const bf16x8*)(As[cur] + (wm + i * 16 + fr) * GBK + fk);
#pragma unroll
        for (int j = 0; j < 4; j++)
            bfr[j] = *(const bf16x8*)(Bs[cur] + (wn + j * 16 + fr) * GBK + fk);
#pragma unroll
        for (int i = 0; i < 4; i++)
#pragma unroll
            for (int j = 0; j < 4; j++)
                acc[i][j] = __builtin_amdgcn_mfma_f32_16x16x32_bf16(af[i], bfr[j], acc[i][j], 0, 0, 0);
    }

    const int crow0 = (lane >> 4) * 4;
    const int col0  = blockIdx.y * GBN + wn;       // 64-aligned
    const int which = col0 >> 10;                  // 0=q 1=k 2=v
    const int hh    = (col0 >> 6) & 15;
    ushort* outp = qkvh + (size_t)which * 4194304 + (size_t)hh * 131072;

    if (which < 2) {
        const float inva = exp2f((float)fr * -0.41524101186f);
        const float invb = exp2f((float)(fr + 16) * -0.41524101186f);
        const float qs = (which == 0) ? 0.125f : 1.0f;
#pragma unroll
        for (int i = 0; i < 4; i++)
#pragma unroll
            for (int r = 0; r < 4; r++) {
                int row = blockIdx.x * GBM + wm + i * 16 + crow0 + r;
                int t = row & 2047;
                size_t ob = ((size_t)(row >> 11)) * 2097152 + (size_t)t * 64;
                float sa, ca, sb, cb;
                __sincosf((float)t * inva, &sa, &ca);
                __sincosf((float)t * invb, &sb, &cb);
                float q0 = acc[i][0][r], q1 = acc[i][1][r];
                float q2 = acc[i][2][r], q3 = acc[i][3][r];
                float n0 = (q0 * ca + q2 * sa) * qs;
                float n1 = (q1 * cb + q3 * sb) * qs;
                float n2 = (q2 * ca - q0 * sa) * qs;
                float n3 = (q3 * cb - q1 * sb) * qs;
                outp[ob + fr]      = (ushort)f2bf(n0);
                outp[ob + 16 + fr] = (ushort)f2bf(n1);
                outp[ob + 32 + fr] = (ushort)f2bf(n2);
                outp[ob + 48 + fr] = (ushort)f2bf(n3);
            }
    } else {
#pragma unroll
        for (int i = 0; i < 4; i++)
#pragma unroll
            for (int r = 0; r < 4; r++) {
                int row = blockIdx.x * GBM + wm + i * 16 + crow0 + r;
                int t = row & 2047;
                size_t ob = ((size_t)(row >> 11)) * 2097152 + (size_t)t * 64;
#pragma unroll
                for (int j = 0; j < 4; j++)
                    outp[ob + j * 16 + fr] = (ushort)f2bf(acc[i][j][r]);
            }
    }
}

// ---- out-projection GEMM (fp32 out), same dbuf loop -----------------------
__global__ __launch_bounds__(256) void gemm_bt_kernel(
    const ushort* __restrict__ A, const ushort* __restrict__ Bmat,
    float* __restrict__ C, int M, int N, int K) {
    __shared__ ushort As[2][GBM * GBK];
    __shared__ ushort Bs[2][GBN * GBK];

    const int tid  = threadIdx.x;
    const int lane = tid & 63;
    const int wv   = tid >> 6;
    const int wm   = (wv >> 1) * 64;
    const int wn   = (wv & 1) * 64;

    const ushort* Ab = A + (size_t)blockIdx.x * GBM * K;
    const ushort* Bb = Bmat + (size_t)blockIdx.y * GBN * K;

    f32x4 acc[4][4];
#pragma unroll
    for (int i = 0; i < 4; i++)
#pragma unroll
        for (int j = 0; j < 4; j++) acc[i][j] = (f32x4){0.f, 0.f, 0.f, 0.f};

    const int srow = tid >> 2;
    const int scol = (tid & 3) * 8;
    const int fr = lane & 15;
    const int fk = (lane >> 4) * 8;
    const int nK = K >> 5;

    gload16(Ab + (size_t)srow * K + scol,        As[0] + wv * 512);
    gload16(Ab + (size_t)(srow + 64) * K + scol, As[0] + wv * 512 + 2048);
    gload16(Bb + (size_t)srow * K + scol,        Bs[0] + wv * 512);
    gload16(Bb + (size_t)(srow + 64) * K + scol, Bs[0] + wv * 512 + 2048);

#pragma unroll 1
    for (int it = 0; it < nK; ++it) {
        const int cur = it & 1;
        __syncthreads();
        if (it + 1 < nK) {
            const int k0 = (it + 1) << 5, nxt = cur ^ 1;
            gload16(Ab + (size_t)srow * K + k0 + scol,        As[nxt] + wv * 512);
            gload16(Ab + (size_t)(srow + 64) * K + k0 + scol, As[nxt] + wv * 512 + 2048);
            gload16(Bb + (size_t)srow * K + k0 + scol,        Bs[nxt] + wv * 512);
            gload16(Bb + (size_t)(srow + 64) * K + k0 + scol, Bs[nxt] + wv * 512 + 2048);
        }
        bf16x8 af[4], bfr[4];
#pragma unroll
        for (int i = 0; i < 4; i++)
            af[i] = *(const bf16x8*)(As[cur] + (wm + i * 16 + fr) * GBK + fk);
#pragma unroll
        for (int j = 0; j < 4; j++)
            bfr[j] = *(const bf16x8*)(Bs[cur] + (wn + j * 16 + fr) * GBK + fk);
#pragma unroll
        for (int i = 0; i < 4; i++)
#pragma unroll
            for (int j = 0; j < 4; j++)
                acc[i][j] = __builtin_amdgcn_mfma_f32_16x16x32_bf16(af[i], bfr[j], acc[i][j], 0, 0, 0);
    }

    const int crow0 = (lane >> 4) * 4;
#pragma unroll
    for (int i = 0; i < 4; i++)
#pragma unroll
        for (int j = 0; j < 4; j++)
#pragma unroll
            for (int r = 0; r < 4; r++) {
                int row = blockIdx.x * GBM + wm + i * 16 + crow0 + r;
                int col = blockIdx.y * GBN + wn + j * 16 + fr;
                C[(size_t)row * N + col] = acc[i][j][r];
            }
}

// ---------------------------------------------------------------------------
// Causal flash attention v5. Bq=64 (256 thr, 4 waves), Bk=64, DOUBLE-BUFFERED
// Ks/Vt with ONE barrier per iteration: barrier -> write chunk it+1 from
// prefetch regs into buf[it+1 & 1] -> prefetch chunk it+2 -> compute chunk it
// from buf[it&1]. P round-trip is same-wave (clobber only; validated r9).
// LDS 46 KB -> 3 blocks/CU; grid 16x32=512 = 2/CU resident. Block p does
// q-blocks p and 31-p (uniform 34 chunk-iters). Fixed-max softmax.
// ---------------------------------------------------------------------------
#define NEG_BIG (-1e30f)
constexpr int LP = 72;    // padded row: 64 + 8

__global__ __launch_bounds__(256) void attn_kernel(const ushort* __restrict__ qkvh,
                                                   ushort* __restrict__ y) {
    __shared__ ushort Ks[2][64 * LP];   // 2 x 9216 B
    __shared__ ushort Vt[2][64 * LP];   // 2 x 9216 B
    __shared__ ushort Ps[4][16 * LP];   // 4 x 2304 B

    const int tid  = threadIdx.x;
    const int lane = tid & 63;
    const int wv   = tid >> 6;
    const int pid  = blockIdx.x;        // 0..15
    const int bh   = blockIdx.y;        // 0..31
    const int b    = bh >> 4, h = bh & 15;

    const ushort* qp = qkvh + (size_t)b * 2097152 + (size_t)h * 131072;
    const ushort* kp = qp + 4194304;
    const ushort* vp = qp + 8388608;

    const int fr = lane & 15;
    const int fq = lane >> 4;
    const int fk = fq * 8;

    const int krow = tid >> 2;          // K staging: key 0..63
    const int kcol = (tid & 3) * 16;    // 16 d per thread
    const int vkey = tid & 63;          // V staging: key
    const int vd0  = (tid >> 6) * 16;   // d-group of 16

#pragma unroll 1
    for (int seg = 0; seg < 2; ++seg) {
        const int qb = seg ? (31 - pid) : pid;    // 64-row q-block, 0..31
        const int nIt = qb + 1;                   // chunks of 64 keys

        __syncthreads();   // protect prologue writes vs previous seg's reads

        const int qrow = qb * 64 + wv * 16 + fr;
        bf16x8 qf0 = *(const bf16x8*)(qp + (size_t)qrow * 64 + fk);
        bf16x8 qf1 = *(const bf16x8*)(qp + (size_t)qrow * 64 + 32 + fk);

        f32x4 o[4];
        o[0] = o[1] = o[2] = o[3] = (f32x4){0.f, 0.f, 0.f, 0.f};
        float lacc[4] = {0.f, 0.f, 0.f, 0.f};

        uint4 kr0, kr1, vr0, vr1;
        {   // chunk 0 -> regs -> buf0
            const ushort* sk = kp + (size_t)krow * 64 + kcol;
            kr0 = *(const uint4*)(sk);
            kr1 = *(const uint4*)(sk + 8);
            const ushort* sv = vp + (size_t)vkey * 64 + vd0;
            vr0 = *(const uint4*)(sv);
            vr1 = *(const uint4*)(sv + 8);
            *(uint4*)(Ks[0] + krow * LP + kcol)     = kr0;
            *(uint4*)(Ks[0] + krow * LP + kcol + 8) = kr1;
            unsigned w[8] = {vr0.x, vr0.y, vr0.z, vr0.w, vr1.x, vr1.y, vr1.z, vr1.w};
#pragma unroll
            for (int jj = 0; jj < 8; ++jj) {
                Vt[0][(vd0 + 2 * jj)     * LP + vkey] = (ushort)(w[jj] & 0xFFFFu);
                Vt[0][(vd0 + 2 * jj + 1) * LP + vkey] = (ushort)(w[jj] >> 16);
            }
        }
        if (1 < nIt) {   // prefetch chunk 1
            const ushort* sk = kp + (size_t)(64 + krow) * 64 + kcol;
            kr0 = *(const uint4*)(sk);
            kr1 = *(const uint4*)(sk + 8);
            const ushort* sv = vp + (size_t)(64 + vkey) * 64 + vd0;
            vr0 = *(const uint4*)(sv);
            vr1 = *(const uint4*)(sv + 8);
        }

#pragma unroll 1
        for (int it = 0; it < nIt; ++it) {
            const int cur = it & 1;
            const int k0 = it * 64;
            __syncthreads();   // buf[cur] writes visible; buf[cur^1] readers done
            if (it + 1 < nIt) {
                const int nxt = cur ^ 1;
                *(uint4*)(Ks[nxt] + krow * LP + kcol)     = kr0;
                *(uint4*)(Ks[nxt] + krow * LP + kcol + 8) = kr1;
                unsigned w[8] = {vr0.x, vr0.y, vr0.z, vr0.w, vr1.x, vr1.y, vr1.z, vr1.w};
#pragma unroll
                for (int jj = 0; jj < 8; ++jj) {
                    Vt[nxt][(vd0 + 2 * jj)     * LP + vkey] = (ushort)(w[jj] & 0xFFFFu);
                    Vt[nxt][(vd0 + 2 * jj + 1) * LP + vkey] = (ushort)(w[jj] >> 16);
                }
                if (it + 2 < nIt) {   // prefetch chunk it+2
                    const ushort* sk = kp + (size_t)(k0 + 128 + krow) * 64 + kcol;
                    kr0 = *(const uint4*)(sk);
                    kr1 = *(const uint4*)(sk + 8);
                    const ushort* sv = vp + (size_t)(k0 + 128 + vkey) * 64 + vd0;
                    vr0 = *(const uint4*)(sv);
                    vr1 = *(const uint4*)(sv + 8);
                }
            }

            // S = Q K^T : 4 key-tiles of 16
            f32x4 s[4];
#pragma unroll
            for (int j = 0; j < 4; ++j) {
                bf16x8 kf0 = *(const bf16x8*)(Ks[cur] + (j * 16 + fr) * LP + fk);
                bf16x8 kf1 = *(const bf16x8*)(Ks[cur] + (j * 16 + fr) * LP + 32 + fk);
                f32x4 z = (f32x4){0.f, 0.f, 0.f, 0.f};
                z = __builtin_amdgcn_mfma_f32_16x16x32_bf16(qf0, kf0, z, 0, 0, 0);
                z = __builtin_amdgcn_mfma_f32_16x16x32_bf16(qf1, kf1, z, 0, 0, 0);
                s[j] = z;
            }
            if (it + 1 < nIt) {   // interior chunk: no mask
#pragma unroll
                for (int j = 0; j < 4; ++j)
#pragma unroll
                    for (int r = 0; r < 4; ++r) {
                        float p = __expf(s[j][r]);
                        s[j][r] = p;
                        lacc[r] += p;
                    }
            } else {              // diagonal chunk
                const int rowg = qb * 64 + wv * 16 + fq * 4;
#pragma unroll
                for (int j = 0; j < 4; ++j)
#pragma unroll
                    for (int r = 0; r < 4; ++r) {
                        float v = s[j][r];
                        if ((k0 + j * 16 + fr) > (rowg + r)) v = NEG_BIG;
                        float p = __expf(v);
                        s[j][r] = p;
                        lacc[r] += p;
                    }
            }

            // P round-trip: same-wave region, DS pipe in-order per wave.
            ushort* pw = Ps[wv];
#pragma unroll
            for (int j = 0; j < 4; ++j)
#pragma unroll
                for (int r = 0; r < 4; ++r)
                    pw[(fq * 4 + r) * LP + j * 16 + fr] = (ushort)f2bf(s[j][r]);
            __asm__ volatile("" ::: "memory");

#pragma unroll
            for (int kk = 0; kk < 2; ++kk) {
                bf16x8 pf = *(const bf16x8*)(pw + fr * LP + kk * 32 + fk);
#pragma unroll
                for (int j = 0; j < 4; ++j) {
                    bf16x8 vf = *(const bf16x8*)(Vt[cur] + (j * 16 + fr) * LP + kk * 32 + fk);
                    o[j] = __builtin_amdgcn_mfma_f32_16x16x32_bf16(pf, vf, o[j], 0, 0, 0);
                }
            }
        }

        // epilogue: reduce lacc over the 16 key-lanes, store y[b][t][h*64+d]
#pragma unroll
        for (int msk = 1; msk < 16; msk <<= 1)
#pragma unroll
            for (int r = 0; r < 4; ++r)
                lacc[r] += __shfl_xor(lacc[r], msk, 64);
#pragma unroll
        for (int j = 0; j < 4; ++j)
#pragma unroll
            for (int r = 0; r < 4; ++r) {
                int row = qb * 64 + wv * 16 + fq * 4 + r;
                y[((size_t)b * 2048 + row) * 1024 + h * 64 + j * 16 + fr] =
                    (ushort)f2bf(o[j][r] / lacc[r]);
            }
    }
}

// ---------------------------------------------------------------------------
extern "C" void kernel_launch(void* const* d_in, const int* in_sizes, int n_in,
                              void* d_out, int out_size, void* d_ws, size_t ws_size,
                              hipStream_t stream) {
    const int nx = in_sizes[0];   // 4194304
    const int na = in_sizes[1];   // 3145728
    const int np = in_sizes[2];   // 1048576

    ushort* qkvh = (ushort*)d_ws;                      // [3][2][16][2048][64]
    ushort* yb   = qkvh + (size_t)3 * 4194304;
    ushort* xb   = yb + (size_t)4096 * 1024;
    ushort* wab  = xb + nx;
    ushort* wpb  = wab + na;
    size_t need = ((size_t)3 * 4194304 + (size_t)4096 * 1024 + nx + na + np) * 2;
    if (ws_size < need) return;

    tobf16_all_kernel<<<dim3(4096), 256, 0, stream>>>(
        (const unsigned*)d_in[0], (const unsigned*)d_in[1], (const unsigned*)d_in[2],
        xb, wab, wpb);

    gemm_qkv_rope_kernel<<<dim3(32, 24), 256, 0, stream>>>(xb, wab, qkvh, 1024);
    attn_kernel<<<dim3(16, 32), 256, 0, stream>>>(qkvh, yb);
    gemm_bt_kernel<<<dim3(32, 8), 256, 0, stream>>>(yb, wpb, (float*)d_out, 4096, 1024, 1024);
}

// Round 11
// 193.351 us; speedup vs baseline: 1.0599x; 1.0421x over previous
//
#include <hip/hip_runtime.h>
#include <math.h>

typedef __bf16 bf16x8 __attribute__((ext_vector_type(8)));
typedef float f32x4 __attribute__((ext_vector_type(4)));

__device__ __forceinline__ unsigned f2bf(float f) {
    union { float f; unsigned u; } v; v.f = f;
    return (v.u + 0x7FFFu + ((v.u >> 16) & 1u)) >> 16;
}

// async global->LDS, 16B per lane. LDS dest = wave-uniform base + lane*16.
__device__ __forceinline__ void gload16(const ushort* g, ushort* l) {
    __builtin_amdgcn_global_load_lds(
        (const __attribute__((address_space(1))) void*)g,
        (__attribute__((address_space(3))) void*)l, 16, 0, 0);
}

// ---------------------------------------------------------------------------
// Fused input canonicalization (one launch): fp32 -> bf16 for all 3 inputs.
// ---------------------------------------------------------------------------
__device__ __forceinline__ bool src_is_fp32(const unsigned* s) {
    int sane = 0;
#pragma unroll
    for (int i = 0; i < 64; ++i) {
        unsigned lo = s[i] & 0xFFFFu;
        unsigned e = (lo >> 7) & 0xFF;
        if (lo == 0u || (e >= 100u && e <= 140u)) sane++;
    }
    return sane < 48;
}

__global__ __launch_bounds__(256) void tobf16_all_kernel(
    const unsigned* __restrict__ s0, const unsigned* __restrict__ s1,
    const unsigned* __restrict__ s2,
    ushort* __restrict__ d0, ushort* __restrict__ d1, ushort* __restrict__ d2) {
    const int bx = blockIdx.x;
    const unsigned* src;
    ushort* dst;
    int lb;
    if (bx < 2048)      { src = s0; dst = d0; lb = bx; }
    else if (bx < 3584) { src = s1; dst = d1; lb = bx - 2048; }
    else                { src = s2; dst = d2; lb = bx - 3584; }
    const int i = lb * 2048 + threadIdx.x * 8;
    if (src_is_fp32(src)) {
        const float* fs = (const float*)src;
        float4 f0 = *(const float4*)(fs + i);
        float4 f1 = *(const float4*)(fs + i + 4);
        uint4 o;
        o.x = f2bf(f0.x) | (f2bf(f0.y) << 16);
        o.y = f2bf(f0.z) | (f2bf(f0.w) << 16);
        o.z = f2bf(f1.x) | (f2bf(f1.y) << 16);
        o.w = f2bf(f1.z) | (f2bf(f1.w) << 16);
        *(uint4*)(dst + i) = o;
    } else {
        *(uint4*)(dst + i) = *(const uint4*)((const ushort*)src + i);
    }
}

// ---------------------------------------------------------------------------
// GEMM K-loop: double-buffered LDS + global_load_lds issued one compute-phase
// ahead of its consuming barrier (validated win, round 10).
// ---------------------------------------------------------------------------
constexpr int GBM = 128, GBN = 128, GBK = 32;

// ---- GEMM1 + RoPE + head-major remap --------------------------------------
__global__ __launch_bounds__(256) void gemm_qkv_rope_kernel(
    const ushort* __restrict__ A, const ushort* __restrict__ Bmat,
    ushort* __restrict__ qkvh, int K) {
    __shared__ ushort As[2][GBM * GBK];
    __shared__ ushort Bs[2][GBN * GBK];

    const int tid  = threadIdx.x;
    const int lane = tid & 63;
    const int wv   = tid >> 6;
    const int wm   = (wv >> 1) * 64;
    const int wn   = (wv & 1) * 64;

    const ushort* Ab = A + (size_t)blockIdx.x * GBM * K;
    const ushort* Bb = Bmat + (size_t)blockIdx.y * GBN * K;

    f32x4 acc[4][4];
#pragma unroll
    for (int i = 0; i < 4; i++)
#pragma unroll
        for (int j = 0; j < 4; j++) acc[i][j] = (f32x4){0.f, 0.f, 0.f, 0.f};

    const int srow = tid >> 2;
    const int scol = (tid & 3) * 8;
    const int fr = lane & 15;
    const int fk = (lane >> 4) * 8;
    const int nK = K >> 5;

    gload16(Ab + (size_t)srow * K + scol,        As[0] + wv * 512);
    gload16(Ab + (size_t)(srow + 64) * K + scol, As[0] + wv * 512 + 2048);
    gload16(Bb + (size_t)srow * K + scol,        Bs[0] + wv * 512);
    gload16(Bb + (size_t)(srow + 64) * K + scol, Bs[0] + wv * 512 + 2048);

#pragma unroll 1
    for (int it = 0; it < nK; ++it) {
        const int cur = it & 1;
        __syncthreads();
        if (it + 1 < nK) {
            const int k0 = (it + 1) << 5, nxt = cur ^ 1;
            gload16(Ab + (size_t)srow * K + k0 + scol,        As[nxt] + wv * 512);
            gload16(Ab + (size_t)(srow + 64) * K + k0 + scol, As[nxt] + wv * 512 + 2048);
            gload16(Bb + (size_t)srow * K + k0 + scol,        Bs[nxt] + wv * 512);
            gload16(Bb + (size_t)(srow + 64) * K + k0 + scol, Bs[nxt] + wv * 512 + 2048);
        }
        bf16x8 af[4], bfr[4];
#pragma unroll
        for (int i = 0; i < 4; i++)
            af[i] = *(const bf16x8*)(As[cur] + (wm + i * 16 + fr) * GBK + fk);
#pragma unroll
        for (int j = 0; j < 4; j++)
            bfr[j] = *(const bf16x8*)(Bs[cur] + (wn + j * 16 + fr) * GBK + fk);
#pragma unroll
        for (int i = 0; i < 4; i++)
#pragma unroll
            for (int j = 0; j < 4; j++)
                acc[i][j] = __builtin_amdgcn_mfma_f32_16x16x32_bf16(af[i], bfr[j], acc[i][j], 0, 0, 0);
    }

    const int crow0 = (lane >> 4) * 4;
    const int col0  = blockIdx.y * GBN + wn;       // 64-aligned
    const int which = col0 >> 10;                  // 0=q 1=k 2=v
    const int hh    = (col0 >> 6) & 15;
    ushort* outp = qkvh + (size_t)which * 4194304 + (size_t)hh * 131072;

    if (which < 2) {
        const float inva = exp2f((float)fr * -0.41524101186f);
        const float invb = exp2f((float)(fr + 16) * -0.41524101186f);
        const float qs = (which == 0) ? 0.125f : 1.0f;
#pragma unroll
        for (int i = 0; i < 4; i++)
#pragma unroll
            for (int r = 0; r < 4; r++) {
                int row = blockIdx.x * GBM + wm + i * 16 + crow0 + r;
                int t = row & 2047;
                size_t ob = ((size_t)(row >> 11)) * 2097152 + (size_t)t * 64;
                float sa, ca, sb, cb;
                __sincosf((float)t * inva, &sa, &ca);
                __sincosf((float)t * invb, &sb, &cb);
                float q0 = acc[i][0][r], q1 = acc[i][1][r];
                float q2 = acc[i][2][r], q3 = acc[i][3][r];
                float n0 = (q0 * ca + q2 * sa) * qs;
                float n1 = (q1 * cb + q3 * sb) * qs;
                float n2 = (q2 * ca - q0 * sa) * qs;
                float n3 = (q3 * cb - q1 * sb) * qs;
                outp[ob + fr]      = (ushort)f2bf(n0);
                outp[ob + 16 + fr] = (ushort)f2bf(n1);
                outp[ob + 32 + fr] = (ushort)f2bf(n2);
                outp[ob + 48 + fr] = (ushort)f2bf(n3);
            }
    } else {
#pragma unroll
        for (int i = 0; i < 4; i++)
#pragma unroll
            for (int r = 0; r < 4; r++) {
                int row = blockIdx.x * GBM + wm + i * 16 + crow0 + r;
                int t = row & 2047;
                size_t ob = ((size_t)(row >> 11)) * 2097152 + (size_t)t * 64;
#pragma unroll
                for (int j = 0; j < 4; j++)
                    outp[ob + j * 16 + fr] = (ushort)f2bf(acc[i][j][r]);
            }
    }
}

// ---- out-projection GEMM (fp32 out), same dbuf loop -----------------------
__global__ __launch_bounds__(256) void gemm_bt_kernel(
    const ushort* __restrict__ A, const ushort* __restrict__ Bmat,
    float* __restrict__ C, int M, int N, int K) {
    __shared__ ushort As[2][GBM * GBK];
    __shared__ ushort Bs[2][GBN * GBK];

    const int tid  = threadIdx.x;
    const int lane = tid & 63;
    const int wv   = tid >> 6;
    const int wm   = (wv >> 1) * 64;
    const int wn   = (wv & 1) * 64;

    const ushort* Ab = A + (size_t)blockIdx.x * GBM * K;
    const ushort* Bb = Bmat + (size_t)blockIdx.y * GBN * K;

    f32x4 acc[4][4];
#pragma unroll
    for (int i = 0; i < 4; i++)
#pragma unroll
        for (int j = 0; j < 4; j++) acc[i][j] = (f32x4){0.f, 0.f, 0.f, 0.f};

    const int srow = tid >> 2;
    const int scol = (tid & 3) * 8;
    const int fr = lane & 15;
    const int fk = (lane >> 4) * 8;
    const int nK = K >> 5;

    gload16(Ab + (size_t)srow * K + scol,        As[0] + wv * 512);
    gload16(Ab + (size_t)(srow + 64) * K + scol, As[0] + wv * 512 + 2048);
    gload16(Bb + (size_t)srow * K + scol,        Bs[0] + wv * 512);
    gload16(Bb + (size_t)(srow + 64) * K + scol, Bs[0] + wv * 512 + 2048);

#pragma unroll 1
    for (int it = 0; it < nK; ++it) {
        const int cur = it & 1;
        __syncthreads();
        if (it + 1 < nK) {
            const int k0 = (it + 1) << 5, nxt = cur ^ 1;
            gload16(Ab + (size_t)srow * K + k0 + scol,        As[nxt] + wv * 512);
            gload16(Ab + (size_t)(srow + 64) * K + k0 + scol, As[nxt] + wv * 512 + 2048);
            gload16(Bb + (size_t)srow * K + k0 + scol,        Bs[nxt] + wv * 512);
            gload16(Bb + (size_t)(srow + 64) * K + k0 + scol, Bs[nxt] + wv * 512 + 2048);
        }
        bf16x8 af[4], bfr[4];
#pragma unroll
        for (int i = 0; i < 4; i++)
            af[i] = *(const bf16x8*)(As[cur] + (wm + i * 16 + fr) * GBK + fk);
#pragma unroll
        for (int j = 0; j < 4; j++)
            bfr[j] = *(const bf16x8*)(Bs[cur] + (wn + j * 16 + fr) * GBK + fk);
#pragma unroll
        for (int i = 0; i < 4; i++)
#pragma unroll
            for (int j = 0; j < 4; j++)
                acc[i][j] = __builtin_amdgcn_mfma_f32_16x16x32_bf16(af[i], bfr[j], acc[i][j], 0, 0, 0);
    }

    const int crow0 = (lane >> 4) * 4;
#pragma unroll
    for (int i = 0; i < 4; i++)
#pragma unroll
        for (int j = 0; j < 4; j++)
#pragma unroll
            for (int r = 0; r < 4; r++) {
                int row = blockIdx.x * GBM + wm + i * 16 + crow0 + r;
                int col = blockIdx.y * GBN + wn + j * 16 + fr;
                C[(size_t)row * N + col] = acc[i][j][r];
            }
}

// ---------------------------------------------------------------------------
// Causal flash attention v6 = r8 shape + r10 pipeline + r9 P-fence:
// Bq=128 (512 thr, 8 waves), Bk=128, paired (p,15-p) -> uniform 17 iters,
// FETCH ~71 MB. Ks/Vt DOUBLE-BUFFERED, ONE barrier/iter (write buf[it+1]
// from prefetch regs, issue prefetch it+2, compute buf[it]). Ps separate,
// same-wave round-trip with asm clobber only. LDS 106 KB -> 1 block/CU
// (grid 256 = 1/CU; 8 waves overlap within the block).
// ---------------------------------------------------------------------------
#define NEG_BIG (-1e30f)
constexpr int LPK = 72;    // Ks row: 64 d + 8 pad
constexpr int LPV = 136;   // Vt/Ps row: 128 keys + 8 pad

__global__ __launch_bounds__(512) void attn_kernel(const ushort* __restrict__ qkvh,
                                                   ushort* __restrict__ y) {
    __shared__ ushort Ks[2][128 * LPK];   // 2 x 18432 B
    __shared__ ushort Vt[2][64 * LPV];    // 2 x 17408 B
    __shared__ ushort Ps[8][16 * LPV];    // 8 x  4352 B

    const int tid  = threadIdx.x;
    const int lane = tid & 63;
    const int wv   = tid >> 6;          // 0..7
    const int pid  = blockIdx.x;        // 0..7
    const int bh   = blockIdx.y;        // 0..31
    const int b    = bh >> 4, h = bh & 15;

    const ushort* qp = qkvh + (size_t)b * 2097152 + (size_t)h * 131072;
    const ushort* kp = qp + 4194304;
    const ushort* vp = qp + 8388608;

    const int fr = lane & 15;
    const int fq = lane >> 4;
    const int fk = fq * 8;

    const int srow = tid >> 2;          // K staging: key 0..127
    const int scol = (tid & 3) * 16;    // 16 d per thread
    const int vkey = tid & 127;         // V staging: key
    const int vd0  = (tid >> 7) * 16;   // d-group of 16

#pragma unroll 1
    for (int seg = 0; seg < 2; ++seg) {
        const int qb = seg ? (15 - pid) : pid;    // 128-row q-block, 0..15
        const int nIt = qb + 1;

        __syncthreads();   // protect buf0 writes vs previous seg's readers

        const int qrow = qb * 128 + wv * 16 + fr;
        bf16x8 qf0 = *(const bf16x8*)(qp + (size_t)qrow * 64 + fk);
        bf16x8 qf1 = *(const bf16x8*)(qp + (size_t)qrow * 64 + 32 + fk);

        f32x4 o[4];
        o[0] = o[1] = o[2] = o[3] = (f32x4){0.f, 0.f, 0.f, 0.f};
        float lacc[4] = {0.f, 0.f, 0.f, 0.f};

        uint4 kr0, kr1, vr0, vr1;
        {   // chunk 0 -> buf 0 (direct)
            const ushort* sk = kp + (size_t)srow * 64 + scol;
            kr0 = *(const uint4*)(sk);
            kr1 = *(const uint4*)(sk + 8);
            const ushort* sv = vp + (size_t)vkey * 64 + vd0;
            vr0 = *(const uint4*)(sv);
            vr1 = *(const uint4*)(sv + 8);
            *(uint4*)(Ks[0] + srow * LPK + scol)     = kr0;
            *(uint4*)(Ks[0] + srow * LPK + scol + 8) = kr1;
            unsigned w[8] = {vr0.x, vr0.y, vr0.z, vr0.w, vr1.x, vr1.y, vr1.z, vr1.w};
#pragma unroll
            for (int jj = 0; jj < 8; ++jj) {
                Vt[0][(vd0 + 2 * jj)     * LPV + vkey] = (ushort)(w[jj] & 0xFFFFu);
                Vt[0][(vd0 + 2 * jj + 1) * LPV + vkey] = (ushort)(w[jj] >> 16);
            }
        }
        if (1 < nIt) {   // prefetch chunk 1 into regs
            const ushort* sk = kp + (size_t)(128 + srow) * 64 + scol;
            kr0 = *(const uint4*)(sk);
            kr1 = *(const uint4*)(sk + 8);
            const ushort* sv = vp + (size_t)(128 + vkey) * 64 + vd0;
            vr0 = *(const uint4*)(sv);
            vr1 = *(const uint4*)(sv + 8);
        }

#pragma unroll 1
        for (int it = 0; it < nIt; ++it) {
            const int cur = it & 1;
            const int k0 = it * 128;
            __syncthreads();   // buf[cur] visible; buf[cur^1] readers done
            if (it + 1 < nIt) {
                const int nxt = cur ^ 1;
                *(uint4*)(Ks[nxt] + srow * LPK + scol)     = kr0;
                *(uint4*)(Ks[nxt] + srow * LPK + scol + 8) = kr1;
                unsigned w[8] = {vr0.x, vr0.y, vr0.z, vr0.w, vr1.x, vr1.y, vr1.z, vr1.w};
#pragma unroll
                for (int jj = 0; jj < 8; ++jj) {
                    Vt[nxt][(vd0 + 2 * jj)     * LPV + vkey] = (ushort)(w[jj] & 0xFFFFu);
                    Vt[nxt][(vd0 + 2 * jj + 1) * LPV + vkey] = (ushort)(w[jj] >> 16);
                }
                if (it + 2 < nIt) {   // prefetch chunk it+2 (in flight a full iter)
                    const ushort* sk = kp + (size_t)(k0 + 256 + srow) * 64 + scol;
                    kr0 = *(const uint4*)(sk);
                    kr1 = *(const uint4*)(sk + 8);
                    const ushort* sv = vp + (size_t)(k0 + 256 + vkey) * 64 + vd0;
                    vr0 = *(const uint4*)(sv);
                    vr1 = *(const uint4*)(sv + 8);
                }
            }

            // S = Q K^T : 8 key-tiles of 16
            f32x4 s[8];
#pragma unroll
            for (int j = 0; j < 8; ++j) {
                bf16x8 kf0 = *(const bf16x8*)(Ks[cur] + (j * 16 + fr) * LPK + fk);
                bf16x8 kf1 = *(const bf16x8*)(Ks[cur] + (j * 16 + fr) * LPK + 32 + fk);
                f32x4 z = (f32x4){0.f, 0.f, 0.f, 0.f};
                z = __builtin_amdgcn_mfma_f32_16x16x32_bf16(qf0, kf0, z, 0, 0, 0);
                z = __builtin_amdgcn_mfma_f32_16x16x32_bf16(qf1, kf1, z, 0, 0, 0);
                s[j] = z;
            }
            if (it + 1 < nIt) {   // interior: no mask
#pragma unroll
                for (int j = 0; j < 8; ++j)
#pragma unroll
                    for (int r = 0; r < 4; ++r) {
                        float p = __expf(s[j][r]);
                        s[j][r] = p;
                        lacc[r] += p;
                    }
            } else {              // diagonal chunk
                const int rowg = qb * 128 + wv * 16 + fq * 4;
#pragma unroll
                for (int j = 0; j < 8; ++j)
#pragma unroll
                    for (int r = 0; r < 4; ++r) {
                        float v = s[j][r];
                        if ((k0 + j * 16 + fr) > (rowg + r)) v = NEG_BIG;
                        float p = __expf(v);
                        s[j][r] = p;
                        lacc[r] += p;
                    }
            }

            // P round-trip: same-wave region, DS in-order per wave.
            ushort* pw = Ps[wv];
#pragma unroll
            for (int j = 0; j < 8; ++j)
#pragma unroll
                for (int r = 0; r < 4; ++r)
                    pw[(fq * 4 + r) * LPV + j * 16 + fr] = (ushort)f2bf(s[j][r]);
            __asm__ volatile("" ::: "memory");

#pragma unroll
            for (int kk = 0; kk < 4; ++kk) {
                bf16x8 pf = *(const bf16x8*)(pw + fr * LPV + kk * 32 + fk);
#pragma unroll
                for (int j = 0; j < 4; ++j) {
                    bf16x8 vf = *(const bf16x8*)(Vt[cur] + (j * 16 + fr) * LPV + kk * 32 + fk);
                    o[j] = __builtin_amdgcn_mfma_f32_16x16x32_bf16(pf, vf, o[j], 0, 0, 0);
                }
            }
        }

        // epilogue: reduce lacc over the 16 key-lanes, store y[b][t][h*64+d]
#pragma unroll
        for (int msk = 1; msk < 16; msk <<= 1)
#pragma unroll
            for (int r = 0; r < 4; ++r)
                lacc[r] += __shfl_xor(lacc[r], msk, 64);
#pragma unroll
        for (int j = 0; j < 4; ++j)
#pragma unroll
            for (int r = 0; r < 4; ++r) {
                int row = qb * 128 + wv * 16 + fq * 4 + r;
                y[((size_t)b * 2048 + row) * 1024 + h * 64 + j * 16 + fr] =
                    (ushort)f2bf(o[j][r] / lacc[r]);
            }
    }
}

// ---------------------------------------------------------------------------
extern "C" void kernel_launch(void* const* d_in, const int* in_sizes, int n_in,
                              void* d_out, int out_size, void* d_ws, size_t ws_size,
                              hipStream_t stream) {
    const int nx = in_sizes[0];   // 4194304
    const int na = in_sizes[1];   // 3145728
    const int np = in_sizes[2];   // 1048576

    ushort* qkvh = (ushort*)d_ws;                      // [3][2][16][2048][64]
    ushort* yb   = qkvh + (size_t)3 * 4194304;
    ushort* xb   = yb + (size_t)4096 * 1024;
    ushort* wab  = xb + nx;
    ushort* wpb  = wab + na;
    size_t need = ((size_t)3 * 4194304 + (size_t)4096 * 1024 + nx + na + np) * 2;
    if (ws_size < need) return;

    tobf16_all_kernel<<<dim3(4096), 256, 0, stream>>>(
        (const unsigned*)d_in[0], (const unsigned*)d_in[1], (const unsigned*)d_in[2],
        xb, wab, wpb);

    gemm_qkv_rope_kernel<<<dim3(32, 24), 256, 0, stream>>>(xb, wab, qkvh, 1024);
    attn_kernel<<<dim3(8, 32), 512, 0, stream>>>(qkvh, yb);
    gemm_bt_kernel<<<dim3(32, 8), 256, 0, stream>>>(yb, wpb, (float*)d_out, 4096, 1024, 1024);
}